// Round 2
// baseline (1292.818 us; speedup 1.0000x reference)
//
#include <hip/hip_runtime.h>
#include <hip/hip_bf16.h>

#define NB 8
#define CC 128
#define HH 112
#define WW 112
#define HWS (HH*WW)            // 12544
#define PLANE (CC*HWS)         // 1605632
#define TOT (NB*PLANE)         // 12845056

__device__ __forceinline__ float bflo(unsigned u){ return __uint_as_float(u<<16); }
__device__ __forceinline__ float bfhi(unsigned u){ return __uint_as_float(u & 0xffff0000u); }
__device__ __forceinline__ float ldv(const float* p, int i){ return p[i]; }
__device__ __forceinline__ float ldv(const ushort* p, int i){ return __uint_as_float(((unsigned)p[i])<<16); }
__device__ __forceinline__ void ld8(const ushort* p, float* v){
    uint4 u = *((const uint4*)p);
    v[0]=bflo(u.x); v[1]=bfhi(u.x); v[2]=bflo(u.y); v[3]=bfhi(u.y);
    v[4]=bflo(u.z); v[5]=bfhi(u.z); v[6]=bflo(u.w); v[7]=bfhi(u.w);
}
__device__ __forceinline__ void ld8(const float* p, float* v){
    float4 a = *((const float4*)p); float4 b = *((const float4*)(p+4));
    v[0]=a.x; v[1]=a.y; v[2]=a.z; v[3]=a.w; v[4]=b.x; v[5]=b.y; v[6]=b.z; v[7]=b.w;
}
__device__ __forceinline__ void ld16(const ushort* p, float* v){ ld8(p,v); ld8(p+8,v+8); }
__device__ __forceinline__ void ld16(const float* p, float* v){ ld8(p,v); ld8(p+8,v+8); }
__device__ __forceinline__ ushort f2bf(float f){
    unsigned u = __float_as_uint(f);
    return (ushort)((u + 0x7fffu + ((u>>16)&1u)) >> 16);
}
__device__ __forceinline__ void stv(float* o, int i, float v){ o[i]=v; }
__device__ __forceinline__ void stv(ushort* o, int i, float v){ o[i]=f2bf(v); }

// ---------------- K0: dtype probe. flag=1 -> inputs are fp32 ----------------
__global__ __launch_bounds__(256) void detect_k(const ushort* __restrict__ x, int* __restrict__ flag){
    __shared__ int cnt;
    if (threadIdx.x==0) cnt = 0;
    __syncthreads();
    int bad = 0;
    for (int i = threadIdx.x; i < 2048; i += 256){
        float v = ldv(x, i);
        if (!(v > -1e4f && v < 1e4f)) bad++;   // NaN also counts
    }
    atomicAdd(&cnt, bad);
    __syncthreads();
    if (threadIdx.x==0) *flag = (cnt > 64) ? 1 : 0;
}

// ---------------- K1: t2 = silu(x) ----------------
template<typename ET>
__device__ __forceinline__ void silu_body(const ET* __restrict__ x, float* __restrict__ t2){
    int i = (blockIdx.x*256 + threadIdx.x)*8;
    float v[8]; ld8(x+i, v);
    float o[8];
    #pragma unroll
    for (int j=0;j<8;j++){ float s = 1.f/(1.f+expf(-v[j])); o[j] = v[j]*s; }
    *((float4*)(t2+i))   = make_float4(o[0],o[1],o[2],o[3]);
    *((float4*)(t2+i+4)) = make_float4(o[4],o[5],o[6],o[7]);
}
__global__ __launch_bounds__(256) void silu_k(const void* x, float* t2, const int* fl){
    if (*fl) silu_body((const float*)x, t2); else silu_body((const ushort*)x, t2);
}

// ---------------- K2: t3 = conv(t2, w3, k=(1,3), dil=(1,2), pad=(0,2)) ----------------
template<typename ET>
__device__ __forceinline__ void conv3_body(const float* __restrict__ t2, const ET* __restrict__ w3,
                                           float* __restrict__ t3){
    int n = blockIdx.x / HH, y = blockIdx.x % HH;
    __shared__ float row[CC*116];
    const float* src = t2 + n*PLANE + y*WW;
    for (int idx = threadIdx.x; idx < CC*WW; idx += 256){
        int i = idx/WW, x = idx - i*WW;
        row[i*116 + x + 2] = src[i*HWS + x];
    }
    for (int idx = threadIdx.x; idx < CC*4; idx += 256){
        int i = idx>>2, j = idx&3;
        row[i*116 + (j<2 ? j : j+112)] = 0.f;
    }
    __syncthreads();
    float* dst = t3 + n*PLANE + y*WW;
    for (int t = threadIdx.x; t < 32*WW; t += 256){
        int oq = t/WW, x = t - oq*WW;
        float a0=0.f,a1=0.f,a2=0.f,a3=0.f;
        const float* r = row + x;
        const ET* wq = w3 + oq*384;
        #pragma unroll 4
        for (int i=0;i<CC;i++){
            float v0 = r[i*116], v1 = r[i*116+2], v2 = r[i*116+4];
            const ET* w = wq + i*3;
            a0 = fmaf(ldv(w,0),v0, fmaf(ldv(w,1),v1, fmaf(ldv(w,2),v2, a0)));
            a1 = fmaf(ldv(w,12288),v0, fmaf(ldv(w,12289),v1, fmaf(ldv(w,12290),v2, a1)));
            a2 = fmaf(ldv(w,24576),v0, fmaf(ldv(w,24577),v1, fmaf(ldv(w,24578),v2, a2)));
            a3 = fmaf(ldv(w,36864),v0, fmaf(ldv(w,36865),v1, fmaf(ldv(w,36866),v2, a3)));
        }
        dst[oq*HWS + x]       = a0;
        dst[(oq+32)*HWS + x]  = a1;
        dst[(oq+64)*HWS + x]  = a2;
        dst[(oq+96)*HWS + x]  = a3;
    }
}
__global__ __launch_bounds__(256) void conv3_k(const float* t2, const void* w3, float* t3, const int* fl){
    if (*fl) conv3_body(t2, (const float*)w3, t3); else conv3_body(t2, (const ushort*)w3, t3);
}

// ---------------- K3: t4 = depthwise conv(t3, w4, k=(7,1), dil=(3,1), pad=(9,0)) ----------------
template<typename ET>
__device__ __forceinline__ void dwconv_body(const float* __restrict__ t3, const ET* __restrict__ w4,
                                            float* __restrict__ t4){
    int c = blockIdx.x & 127, n = blockIdx.x >> 7;
    __shared__ float pl[HWS];
    const float* src = t3 + n*PLANE + c*HWS;
    for (int i=threadIdx.x;i<HWS;i+=256) pl[i]=src[i];
    float wk[7];
    #pragma unroll
    for (int k=0;k<7;k++) wk[k]=ldv(w4, c*7+k);
    __syncthreads();
    float* dst = t4 + n*PLANE + c*HWS;
    for (int i=threadIdx.x;i<HWS;i+=256){
        int y = i/WW, x = i - y*WW;
        float acc=0.f;
        #pragma unroll
        for (int k=0;k<7;k++){
            int yy = y-9+3*k;
            if (yy>=0 && yy<HH) acc = fmaf(wk[k], pl[yy*WW+x], acc);
        }
        dst[i]=acc;
    }
}
__global__ __launch_bounds__(256) void dwconv_k(const float* t3, const void* w4, float* t4, const int* fl){
    if (*fl) dwconv_body(t3, (const float*)w4, t4); else dwconv_body(t3, (const ushort*)w4, t4);
}

// ---------------- KW: Wf[o][cl][k] = w15[o, cl*7+k] * w10[32g+cl, k] ----------------
template<typename ET>
__device__ __forceinline__ void fusew_body(const ET* __restrict__ w10, const ET* __restrict__ w15,
                                           float* __restrict__ Wf){
    int idx = blockIdx.x*256+threadIdx.x;
    if (idx < CC*224){
        int o = idx / 224, r = idx - o*224;
        int g = o >> 5;
        int cl = r/7, k = r - cl*7;
        int c = g*32 + cl;
        Wf[idx] = ldv(w15, o*224 + r) * ldv(w10, c*7+k);
    }
}
__global__ __launch_bounds__(256) void fusew_k(const void* w10, const void* w15, float* Wf, const int* fl){
    if (*fl) fusew_body((const float*)w10, (const float*)w15, Wf);
    else     fusew_body((const ushort*)w10, (const ushort*)w15, Wf);
}

// ---------------- K6: u[n,o,yy,x] = sum_{c,k} Wf[o,c,k] * t4[n,(c-2)%128, yy+2k-6, x] ----------------
__global__ __launch_bounds__(256) void t15_k(const float* __restrict__ t4, const float* __restrict__ Wf,
                                             float* __restrict__ u){
    int yy = blockIdx.x, g = blockIdx.y, n = blockIdx.z;
    __shared__ float sm[32*WW];
    float acc[4][4] = {};
    int tid = threadIdx.x;
    int og = tid / 28, xg = tid - og*28;
    bool active = tid < 224;
    for (int k=0;k<7;k++){
        __syncthreads();
        int row = yy + 2*k - 6;
        for (int idx=tid; idx<32*WW; idx+=256){
            int cl = idx/WW, x = idx - cl*WW;
            int ch = (g*32 + cl - 2) & 127;
            sm[idx] = (row>=0 && row<HH) ? t4[(n*CC+ch)*HWS + row*WW + x] : 0.f;
        }
        __syncthreads();
        if (active){
            const float* wfp = Wf + (g*32 + og*4)*224 + k;
            #pragma unroll 8
            for (int cl=0; cl<32; cl++){
                float4 v = *((const float4*)&sm[cl*WW + xg*4]);
                float w0 = wfp[cl*7], w1 = wfp[cl*7+224], w2 = wfp[cl*7+448], w3v = wfp[cl*7+672];
                acc[0][0]=fmaf(w0,v.x,acc[0][0]); acc[0][1]=fmaf(w0,v.y,acc[0][1]);
                acc[0][2]=fmaf(w0,v.z,acc[0][2]); acc[0][3]=fmaf(w0,v.w,acc[0][3]);
                acc[1][0]=fmaf(w1,v.x,acc[1][0]); acc[1][1]=fmaf(w1,v.y,acc[1][1]);
                acc[1][2]=fmaf(w1,v.z,acc[1][2]); acc[1][3]=fmaf(w1,v.w,acc[1][3]);
                acc[2][0]=fmaf(w2,v.x,acc[2][0]); acc[2][1]=fmaf(w2,v.y,acc[2][1]);
                acc[2][2]=fmaf(w2,v.z,acc[2][2]); acc[2][3]=fmaf(w2,v.w,acc[2][3]);
                acc[3][0]=fmaf(w3v,v.x,acc[3][0]); acc[3][1]=fmaf(w3v,v.y,acc[3][1]);
                acc[3][2]=fmaf(w3v,v.z,acc[3][2]); acc[3][3]=fmaf(w3v,v.w,acc[3][3]);
            }
        }
    }
    if (active){
        #pragma unroll
        for (int a=0;a<4;a++){
            int o = g*32 + og*4 + a;
            float* up = u + (n*CC+o)*HWS + yy*WW + xg*4;
            *((float4*)up) = make_float4(acc[a][0],acc[a][1],acc[a][2],acc[a][3]);
        }
    }
}

// ---------------- K4: t5raw[n,ci,cj] = sum_s sigmoid(x[n,ci,s]) * x[n,cj,s]  (atomic K-split) ----------------
template<typename ET>
__device__ __forceinline__ void t5_body(const ET* __restrict__ x, float* __restrict__ t5){
    int kc = blockIdx.x, n = blockIdx.y;   // kc in 0..31
    __shared__ float sA[32][136];  // sigmoid side [s][ch]
    __shared__ float sB[32][136];  // raw side    [s][ch]
    float acc[8][8] = {};
    int tid = threadIdx.x, ty = tid>>4, tx = tid&15;
    int lch = tid>>1, lhalf = tid&1;
    const ET* xb = x + (size_t)n*PLANE;
    for (int s0 = kc*32; s0 < HWS; s0 += 32*32){
        const ET* p = xb + lch*HWS + s0 + lhalf*16;
        float v[16]; ld16(p, v);
        #pragma unroll
        for (int j=0;j<16;j++){
            sB[lhalf*16+j][lch] = v[j];
            sA[lhalf*16+j][lch] = 1.f/(1.f+expf(-v[j]));
        }
        __syncthreads();
        #pragma unroll 4
        for (int kk=0;kk<32;kk++){
            float a[8], b[8];
            *(float4*)&a[0] = *((const float4*)&sA[kk][ty*8]);
            *(float4*)&a[4] = *((const float4*)&sA[kk][ty*8+4]);
            *(float4*)&b[0] = *((const float4*)&sB[kk][tx*8]);
            *(float4*)&b[4] = *((const float4*)&sB[kk][tx*8+4]);
            #pragma unroll
            for (int i=0;i<8;i++)
                #pragma unroll
                for (int j=0;j<8;j++)
                    acc[i][j] = fmaf(a[i], b[j], acc[i][j]);
        }
        __syncthreads();
    }
    float* t5n = t5 + n*16384;
    #pragma unroll
    for (int i=0;i<8;i++)
        #pragma unroll
        for (int j=0;j<8;j++)
            atomicAdd(&t5n[(ty*8+i)*128 + (tx*8+j)], acc[i][j]);
}
__global__ __launch_bounds__(256) void t5_k(const void* x, float* t5, const int* fl){
    if (*fl) t5_body((const float*)x, t5); else t5_body((const ushort*)x, t5);
}

// ---------------- K5: out = u[shifted] + sc * sum_c (w9[c,d]*t5[n,c,d]) * t2[n,c,s] ----------------
template<typename ET, typename OT>
__device__ __forceinline__ void final_body(const float* __restrict__ t2, const float* __restrict__ t5,
                                           const ET* __restrict__ w9, const float* __restrict__ u,
                                           OT* __restrict__ out){
    int st = blockIdx.x, dt = blockIdx.y, n = blockIdx.z;
    int s0 = st*64, d0 = dt*64;
    __shared__ float sA[16][68];  // coeff [c][d]
    __shared__ float sB[16][68];  // t2    [c][s]
    float acc[4][4]={};
    int tid=threadIdx.x, ty=tid>>4, tx=tid&15;
    const float sc = 7.89181775e-4f;   // 1/(sqrt(12544)*sqrt(128))
    const float* t5n = t5 + n*16384;
    const float* t2n = t2 + (size_t)n*PLANE;
    for (int c0=0; c0<CC; c0+=16){
        for (int idx=tid; idx<1024; idx+=256){
            int cl = idx>>6, dl = idx&63;
            int c = c0+cl;
            sA[cl][dl] = ldv(w9, c*128 + d0+dl) * t5n[c*128 + d0+dl] * sc;
            sB[cl][dl] = t2n[c*HWS + s0 + dl];
        }
        __syncthreads();
        #pragma unroll 4
        for (int kk=0;kk<16;kk++){
            float4 a = *((const float4*)&sA[kk][ty*4]);
            float4 b = *((const float4*)&sB[kk][tx*4]);
            acc[0][0]=fmaf(a.x,b.x,acc[0][0]); acc[0][1]=fmaf(a.x,b.y,acc[0][1]);
            acc[0][2]=fmaf(a.x,b.z,acc[0][2]); acc[0][3]=fmaf(a.x,b.w,acc[0][3]);
            acc[1][0]=fmaf(a.y,b.x,acc[1][0]); acc[1][1]=fmaf(a.y,b.y,acc[1][1]);
            acc[1][2]=fmaf(a.y,b.z,acc[1][2]); acc[1][3]=fmaf(a.y,b.w,acc[1][3]);
            acc[2][0]=fmaf(a.z,b.x,acc[2][0]); acc[2][1]=fmaf(a.z,b.y,acc[2][1]);
            acc[2][2]=fmaf(a.z,b.z,acc[2][2]); acc[2][3]=fmaf(a.z,b.w,acc[2][3]);
            acc[3][0]=fmaf(a.w,b.x,acc[3][0]); acc[3][1]=fmaf(a.w,b.y,acc[3][1]);
            acc[3][2]=fmaf(a.w,b.z,acc[3][2]); acc[3][3]=fmaf(a.w,b.w,acc[3][3]);
        }
        __syncthreads();
    }
    #pragma unroll
    for (int i=0;i<4;i++){
        int d = d0 + ty*4 + i;
        const float* un = u + ((size_t)n*CC+d)*HWS;
        #pragma unroll
        for (int j=0;j<4;j++){
            int s = s0 + tx*4 + j;
            int y = s/WW, x = s - y*WW;
            int ys = y+2; if (ys>=HH) ys-=HH;
            int xs = x-2; if (xs<0) xs+=WW;
            float val = un[ys*WW + xs] + acc[i][j];
            stv(out, ((size_t)n*CC+d)*HWS + s, val);
        }
    }
}
__global__ __launch_bounds__(256) void final_k(const float* t2, const float* t5, const void* w9,
                                               const float* u, void* out, const int* fl){
    if (*fl) final_body((const float*)t2, t5, (const float*)w9, u, (float*)out);
    else     final_body((const float*)t2, t5, (const ushort*)w9, u, (ushort*)out);
}

extern "C" void kernel_launch(void* const* d_in, const int* in_sizes, int n_in,
                              void* d_out, int out_size, void* d_ws, size_t ws_size,
                              hipStream_t stream) {
    const void* x   = d_in[0];
    const void* w3  = d_in[1];
    const void* w4  = d_in[2];
    const void* w9  = d_in[3];
    const void* w10 = d_in[4];
    const void* w15 = d_in[5];

    float* ws = (float*)d_ws;
    float* t2 = ws;                     // TOT
    float* t3 = t2 + TOT;               // TOT (reused as u after dwconv)
    float* t4 = t3 + TOT;               // TOT
    float* t5 = t4 + TOT;               // NB*CC*CC
    float* Wf = t5 + NB*CC*CC;          // CC*224
    int* flag = (int*)(Wf + CC*224);

    detect_k<<<1, 256, 0, stream>>>((const ushort*)x, flag);
    hipMemsetAsync(t5, 0, NB*CC*CC*sizeof(float), stream);

    silu_k  <<<TOT/8/256, 256, 0, stream>>>(x, t2, flag);
    conv3_k <<<NB*HH,     256, 0, stream>>>(t2, w3, t3, flag);
    dwconv_k<<<NB*CC,     256, 0, stream>>>(t3, w4, t4, flag);
    fusew_k <<<112,       256, 0, stream>>>(w10, w15, Wf, flag);
    // t3 buffer is dead now -> reuse it for u (t15 on natural grid)
    t15_k   <<<dim3(HH,4,NB), 256, 0, stream>>>(t4, Wf, t3);
    t5_k    <<<dim3(32,NB),   256, 0, stream>>>(x, t5, flag);
    final_k <<<dim3(HWS/64, CC/64, NB), 256, 0, stream>>>(t2, t5, w9, t3, d_out, flag);
}

// Round 3
// 739.129 us; speedup vs baseline: 1.7491x; 1.7491x over previous
//
#include <hip/hip_runtime.h>
#include <hip/hip_bf16.h>

#define NB 8
#define CC 128
#define HH 112
#define WW 112
#define HWS (HH*WW)            // 12544
#define PLANE (CC*HWS)         // 1605632
#define TOT (NB*PLANE)         // 12845056

typedef __attribute__((ext_vector_type(8))) short short8v;
typedef __attribute__((ext_vector_type(4))) float float4v;

__device__ __forceinline__ float bflo(unsigned u){ return __uint_as_float(u<<16); }
__device__ __forceinline__ float bfhi(unsigned u){ return __uint_as_float(u & 0xffff0000u); }
__device__ __forceinline__ float ldv(const float* p, size_t i){ return p[i]; }
__device__ __forceinline__ float ldv(const ushort* p, size_t i){ return __uint_as_float(((unsigned)p[i])<<16); }
__device__ __forceinline__ void ld16(const ushort* p, float* v){
    uint4 u0 = *((const uint4*)p); uint4 u1 = *((const uint4*)(p+8));
    v[0]=bflo(u0.x); v[1]=bfhi(u0.x); v[2]=bflo(u0.y); v[3]=bfhi(u0.y);
    v[4]=bflo(u0.z); v[5]=bfhi(u0.z); v[6]=bflo(u0.w); v[7]=bfhi(u0.w);
    v[8]=bflo(u1.x); v[9]=bfhi(u1.x); v[10]=bflo(u1.y); v[11]=bfhi(u1.y);
    v[12]=bflo(u1.z); v[13]=bfhi(u1.z); v[14]=bflo(u1.w); v[15]=bfhi(u1.w);
}
__device__ __forceinline__ void ld16(const float* p, float* v){
    #pragma unroll
    for (int j=0;j<16;j++) v[j]=p[j];
}
__device__ __forceinline__ ushort f2bf(float f){
    unsigned u = __float_as_uint(f);
    return (ushort)((u + 0x7fffu + ((u>>16)&1u)) >> 16);
}
__device__ __forceinline__ void stv(float* o, size_t i, float v){ o[i]=v; }
__device__ __forceinline__ void stv(ushort* o, size_t i, float v){ o[i]=f2bf(v); }

// ---------------- K0: dtype probe. flag=1 -> inputs are fp32 ----------------
__global__ __launch_bounds__(256) void detect_k(const ushort* __restrict__ x, int* __restrict__ flag){
    __shared__ int cnt;
    if (threadIdx.x==0) cnt = 0;
    __syncthreads();
    int bad = 0;
    for (int i = threadIdx.x; i < 2048; i += 256){
        float v = ldv(x, i);
        if (!(v > -1e4f && v < 1e4f)) bad++;
    }
    atomicAdd(&cnt, bad);
    __syncthreads();
    if (threadIdx.x==0) *flag = (cnt > 64) ? 1 : 0;
}

// ---------------- KW1: Wpk[o][kappa=k*128+i] = bf16(w3[o,i,0,k]) ----------------
template<typename ET>
__device__ __forceinline__ void wpack_body(const ET* __restrict__ w3, ushort* __restrict__ Wpk){
    int idx = blockIdx.x*256 + threadIdx.x;
    if (idx < CC*384){
        int o = idx/384, kap = idx - o*384;
        int k = kap>>7, i = kap&127;
        Wpk[idx] = f2bf(ldv(w3, (o*128+i)*3 + k));
    }
}
__global__ __launch_bounds__(256) void wpack_k(const void* w3, ushort* Wpk, const int* fl){
    if (*fl) wpack_body((const float*)w3, Wpk); else wpack_body((const ushort*)w3, Wpk);
}

// ---------------- KB: Bbig[s][kappa] = bf16(silu(x)[i, y, x+2k-2]), fragment-ordered im2col ----------------
template<typename ET>
__device__ __forceinline__ void bbig_body(const ET* __restrict__ x, ushort* __restrict__ Bbig){
    int y = blockIdx.x, n = blockIdx.y;
    __shared__ ushort row[CC*120];
    const ET* xb = x + (size_t)n*PLANE + y*WW;
    for (int idx=threadIdx.x; idx<CC*WW; idx+=256){
        int i = idx/WW, xx = idx - i*WW;
        float v = ldv(xb, (size_t)i*HWS + xx);
        float sv = v * (1.f/(1.f+expf(-v)));
        row[i*120 + xx + 2] = f2bf(sv);
    }
    for (int idx=threadIdx.x; idx<CC*4; idx+=256){
        int i = idx>>2, j = idx&3;
        row[i*120 + (j<2 ? j : j+112)] = 0;
    }
    __syncthreads();
    ushort* ob = Bbig + ((size_t)(n*HWS + y*WW))*384;
    for (int idx=threadIdx.x; idx<WW*48; idx+=256){
        int xx = idx/48, c8 = idx - xx*48;
        int k = c8>>4, i0 = (c8&15)<<3, xp = xx + 2*k;
        ushort tmp[8];
        #pragma unroll
        for (int j=0;j<8;j++) tmp[j] = row[(i0+j)*120 + xp];
        *((short8v*)(ob + (size_t)xx*384 + c8*8)) = *((const short8v*)tmp);
    }
}
__global__ __launch_bounds__(256) void bbig_k(const void* x, ushort* Bbig, const int* fl){
    if (*fl) bbig_body((const float*)x, Bbig); else bbig_body((const ushort*)x, Bbig);
}

// ---------------- K2: t3 = A(128x384) * Bbig(384 x s) per n, LDS-free MFMA GEMM ----------------
__global__ __launch_bounds__(256) void conv3mm_k(const ushort* __restrict__ Bbig, const ushort* __restrict__ Wpk,
                                                 float* __restrict__ t3){
    int sb = blockIdx.x;        // 0..97
    int n  = blockIdx.y;
    int wid = threadIdx.x >> 6, lane = threadIdx.x & 63;
    int l15 = lane & 15, quad = lane >> 4;
    int s0 = sb*128 + wid*32;
    const ushort* bbase = Bbig + ((size_t)(n*HWS) + s0 + l15)*384 + quad*8;
    const ushort* abase = Wpk + (size_t)l15*384 + quad*8;
    float4v acc[8][2] = {};
    #pragma unroll
    for (int kc=0; kc<12; kc++){
        short8v b0 = *((const short8v*)(bbase + kc*32));
        short8v b1 = *((const short8v*)(bbase + 16*384 + kc*32));
        #pragma unroll
        for (int mt=0; mt<8; mt++){
            short8v a = *((const short8v*)(abase + (size_t)mt*16*384 + kc*32));
            acc[mt][0] = __builtin_amdgcn_mfma_f32_16x16x32_bf16(a, b0, acc[mt][0], 0,0,0);
            acc[mt][1] = __builtin_amdgcn_mfma_f32_16x16x32_bf16(a, b1, acc[mt][1], 0,0,0);
        }
    }
    float* tb = t3 + (size_t)n*PLANE;
    #pragma unroll
    for (int mt=0; mt<8; mt++){
        #pragma unroll
        for (int nt=0; nt<2; nt++){
            #pragma unroll
            for (int r=0; r<4; r++){
                int o = mt*16 + quad*4 + r;
                int s = s0 + nt*16 + l15;
                tb[(size_t)o*HWS + s] = acc[mt][nt][r];
            }
        }
    }
}

// ---------------- K3: depthwise conv(7,1) dil=(3,1) pad=(9,0) — in-place safe ----------------
template<typename ET>
__device__ __forceinline__ void dwconv_body(const float* __restrict__ t3, const ET* __restrict__ w4,
                                            float* __restrict__ t4){
    int c = blockIdx.x & 127, n = blockIdx.x >> 7;
    __shared__ float pl[HWS];
    const float* src = t3 + (size_t)n*PLANE + c*HWS;
    for (int i=threadIdx.x;i<HWS;i+=256) pl[i]=src[i];
    float wk[7];
    #pragma unroll
    for (int k=0;k<7;k++) wk[k]=ldv(w4, c*7+k);
    __syncthreads();
    float* dst = t4 + (size_t)n*PLANE + c*HWS;
    for (int i=threadIdx.x;i<HWS;i+=256){
        int y = i/WW, x = i - y*WW;
        float acc=0.f;
        #pragma unroll
        for (int k=0;k<7;k++){
            int yy = y-9+3*k;
            if (yy>=0 && yy<HH) acc = fmaf(wk[k], pl[yy*WW+x], acc);
        }
        dst[i]=acc;
    }
}
__global__ __launch_bounds__(256) void dwconv_k(const float* t3, const void* w4, float* t4, const int* fl){
    if (*fl) dwconv_body(t3, (const float*)w4, t4); else dwconv_body(t3, (const ushort*)w4, t4);
}

// ---------------- KW2: Wf[o][cl][k] = w15[o, cl*7+k] * w10[32g+cl, k] ----------------
template<typename ET>
__device__ __forceinline__ void fusew_body(const ET* __restrict__ w10, const ET* __restrict__ w15,
                                           float* __restrict__ Wf){
    int idx = blockIdx.x*256+threadIdx.x;
    if (idx < CC*224){
        int o = idx / 224, r = idx - o*224;
        int g = o >> 5;
        int cl = r/7, k = r - cl*7;
        int c = g*32 + cl;
        Wf[idx] = ldv(w15, o*224 + r) * ldv(w10, c*7+k);
    }
}
__global__ __launch_bounds__(256) void fusew_k(const void* w10, const void* w15, float* Wf, const int* fl){
    if (*fl) fusew_body((const float*)w10, (const float*)w15, Wf);
    else     fusew_body((const ushort*)w10, (const ushort*)w15, Wf);
}

// ---------------- K6: u[n,o,yy,x] = sum_{c,k} Wf[o,c,k] * t4[n,(c-2)%128, yy+2k-6, x] ----------------
__global__ __launch_bounds__(256) void t15_k(const float* __restrict__ t4, const float* __restrict__ Wf,
                                             float* __restrict__ u){
    int yy = blockIdx.x, g = blockIdx.y, n = blockIdx.z;
    __shared__ float sm[32*WW];
    float acc[4][4] = {};
    int tid = threadIdx.x;
    int og = tid / 28, xg = tid - og*28;
    bool active = tid < 224;
    for (int k=0;k<7;k++){
        __syncthreads();
        int row = yy + 2*k - 6;
        for (int idx=tid; idx<32*WW; idx+=256){
            int cl = idx/WW, x = idx - cl*WW;
            int ch = (g*32 + cl - 2) & 127;
            sm[idx] = (row>=0 && row<HH) ? t4[((size_t)n*CC+ch)*HWS + row*WW + x] : 0.f;
        }
        __syncthreads();
        if (active){
            const float* wfp = Wf + (g*32 + og*4)*224 + k;
            #pragma unroll 8
            for (int cl=0; cl<32; cl++){
                float4 v = *((const float4*)&sm[cl*WW + xg*4]);
                float w0 = wfp[cl*7], w1 = wfp[cl*7+224], w2 = wfp[cl*7+448], w3v = wfp[cl*7+672];
                acc[0][0]=fmaf(w0,v.x,acc[0][0]); acc[0][1]=fmaf(w0,v.y,acc[0][1]);
                acc[0][2]=fmaf(w0,v.z,acc[0][2]); acc[0][3]=fmaf(w0,v.w,acc[0][3]);
                acc[1][0]=fmaf(w1,v.x,acc[1][0]); acc[1][1]=fmaf(w1,v.y,acc[1][1]);
                acc[1][2]=fmaf(w1,v.z,acc[1][2]); acc[1][3]=fmaf(w1,v.w,acc[1][3]);
                acc[2][0]=fmaf(w2,v.x,acc[2][0]); acc[2][1]=fmaf(w2,v.y,acc[2][1]);
                acc[2][2]=fmaf(w2,v.z,acc[2][2]); acc[2][3]=fmaf(w2,v.w,acc[2][3]);
                acc[3][0]=fmaf(w3v,v.x,acc[3][0]); acc[3][1]=fmaf(w3v,v.y,acc[3][1]);
                acc[3][2]=fmaf(w3v,v.z,acc[3][2]); acc[3][3]=fmaf(w3v,v.w,acc[3][3]);
            }
        }
    }
    if (active){
        #pragma unroll
        for (int a=0;a<4;a++){
            int o = g*32 + og*4 + a;
            float* up = u + ((size_t)n*CC+o)*HWS + yy*WW + xg*4;
            *((float4*)up) = make_float4(acc[a][0],acc[a][1],acc[a][2],acc[a][3]);
        }
    }
}

// ---------------- K4: t5raw[n,ci,cj] = sum_s sigmoid(x[n,ci,s]) * x[n,cj,s]  (atomic K-split) ----------------
template<typename ET>
__device__ __forceinline__ void t5_body(const ET* __restrict__ x, float* __restrict__ t5){
    int kc = blockIdx.x, n = blockIdx.y;
    __shared__ float sA[32][136];
    __shared__ float sB[32][136];
    float acc[8][8] = {};
    int tid = threadIdx.x, ty = tid>>4, tx = tid&15;
    int lch = tid>>1, lhalf = tid&1;
    const ET* xb = x + (size_t)n*PLANE;
    for (int s0 = kc*32; s0 < HWS; s0 += 32*32){
        const ET* p = xb + (size_t)lch*HWS + s0 + lhalf*16;
        float v[16]; ld16(p, v);
        #pragma unroll
        for (int j=0;j<16;j++){
            sB[lhalf*16+j][lch] = v[j];
            sA[lhalf*16+j][lch] = 1.f/(1.f+expf(-v[j]));
        }
        __syncthreads();
        #pragma unroll 4
        for (int kk=0;kk<32;kk++){
            float a[8], b[8];
            *(float4*)&a[0] = *((const float4*)&sA[kk][ty*8]);
            *(float4*)&a[4] = *((const float4*)&sA[kk][ty*8+4]);
            *(float4*)&b[0] = *((const float4*)&sB[kk][tx*8]);
            *(float4*)&b[4] = *((const float4*)&sB[kk][tx*8+4]);
            #pragma unroll
            for (int i=0;i<8;i++)
                #pragma unroll
                for (int j=0;j<8;j++)
                    acc[i][j] = fmaf(a[i], b[j], acc[i][j]);
        }
        __syncthreads();
    }
    float* t5n = t5 + n*16384;
    #pragma unroll
    for (int i=0;i<8;i++)
        #pragma unroll
        for (int j=0;j<8;j++)
            atomicAdd(&t5n[(ty*8+i)*128 + (tx*8+j)], acc[i][j]);
}
__global__ __launch_bounds__(256) void t5_k(const void* x, float* t5, const int* fl){
    if (*fl) t5_body((const float*)x, t5); else t5_body((const ushort*)x, t5);
}

// ---------------- K5: out = u[shifted] + sc * sum_c (w9[c,d]*t5[n,c,d]) * silu(x)[n,c,s] ----------------
template<typename ET, typename OT>
__device__ __forceinline__ void final_body(const ET* __restrict__ x, const float* __restrict__ t5,
                                           const ET* __restrict__ w9, const float* __restrict__ u,
                                           OT* __restrict__ out){
    int st = blockIdx.x, dt = blockIdx.y, n = blockIdx.z;
    int s0 = st*64, d0 = dt*64;
    __shared__ float sA[16][68];
    __shared__ float sB[16][68];
    float acc[4][4]={};
    int tid=threadIdx.x, ty=tid>>4, tx=tid&15;
    const float sc = 7.89181775e-4f;   // 1/(sqrt(12544)*sqrt(128))
    const float* t5n = t5 + n*16384;
    const ET* xn = x + (size_t)n*PLANE;
    for (int c0=0; c0<CC; c0+=16){
        for (int idx=tid; idx<1024; idx+=256){
            int cl = idx>>6, dl = idx&63;
            int c = c0+cl;
            sA[cl][dl] = ldv(w9, c*128 + d0+dl) * t5n[c*128 + d0+dl] * sc;
            float v = ldv(xn, (size_t)c*HWS + s0 + dl);
            sB[cl][dl] = v * (1.f/(1.f+expf(-v)));
        }
        __syncthreads();
        #pragma unroll 4
        for (int kk=0;kk<16;kk++){
            float4 a = *((const float4*)&sA[kk][ty*4]);
            float4 b = *((const float4*)&sB[kk][tx*4]);
            acc[0][0]=fmaf(a.x,b.x,acc[0][0]); acc[0][1]=fmaf(a.x,b.y,acc[0][1]);
            acc[0][2]=fmaf(a.x,b.z,acc[0][2]); acc[0][3]=fmaf(a.x,b.w,acc[0][3]);
            acc[1][0]=fmaf(a.y,b.x,acc[1][0]); acc[1][1]=fmaf(a.y,b.y,acc[1][1]);
            acc[1][2]=fmaf(a.y,b.z,acc[1][2]); acc[1][3]=fmaf(a.y,b.w,acc[1][3]);
            acc[2][0]=fmaf(a.z,b.x,acc[2][0]); acc[2][1]=fmaf(a.z,b.y,acc[2][1]);
            acc[2][2]=fmaf(a.z,b.z,acc[2][2]); acc[2][3]=fmaf(a.z,b.w,acc[2][3]);
            acc[3][0]=fmaf(a.w,b.x,acc[3][0]); acc[3][1]=fmaf(a.w,b.y,acc[3][1]);
            acc[3][2]=fmaf(a.w,b.z,acc[3][2]); acc[3][3]=fmaf(a.w,b.w,acc[3][3]);
        }
        __syncthreads();
    }
    #pragma unroll
    for (int i=0;i<4;i++){
        int d = d0 + ty*4 + i;
        const float* un = u + ((size_t)n*CC+d)*HWS;
        #pragma unroll
        for (int j=0;j<4;j++){
            int s = s0 + tx*4 + j;
            int y = s/WW, xx = s - y*WW;
            int ys = y+2; if (ys>=HH) ys-=HH;
            int xs = xx-2; if (xs<0) xs+=WW;
            float val = un[ys*WW + xs] + acc[i][j];
            stv(out, ((size_t)n*CC+d)*HWS + s, val);
        }
    }
}
__global__ __launch_bounds__(256) void final_k(const void* x, const float* t5, const void* w9,
                                               const float* u, void* out, const int* fl){
    if (*fl) final_body((const float*)x, t5, (const float*)w9, u, (float*)out);
    else     final_body((const ushort*)x, t5, (const ushort*)w9, u, (ushort*)out);
}

extern "C" void kernel_launch(void* const* d_in, const int* in_sizes, int n_in,
                              void* d_out, int out_size, void* d_ws, size_t ws_size,
                              hipStream_t stream) {
    const void* x   = d_in[0];
    const void* w3  = d_in[1];
    const void* w4  = d_in[2];
    const void* w9  = d_in[3];
    const void* w10 = d_in[4];
    const void* w15 = d_in[5];

    float* ws = (float*)d_ws;
    float* t3   = ws;                               // TOT floats (t3, then t4 in-place)
    ushort* Bbig = (ushort*)(ws + TOT);             // 8*12544*384 ushorts = 77MB
    float* u    = (float*)Bbig;                     // aliases Bbig (dead after conv3mm)
    float* t5   = ws + TOT + 19267584;              // after Bbig region
    float* Wf   = t5 + NB*CC*CC;                    // 131072 floats
    ushort* Wpk = (ushort*)(Wf + CC*224);           // 49152 ushorts
    int* flag   = (int*)(Wpk + CC*384);

    detect_k<<<1, 256, 0, stream>>>((const ushort*)x, flag);
    hipMemsetAsync(t5, 0, NB*CC*CC*sizeof(float), stream);

    wpack_k <<<192, 256, 0, stream>>>(w3, Wpk, flag);
    fusew_k <<<112, 256, 0, stream>>>(w10, w15, Wf, flag);
    bbig_k  <<<dim3(HH,NB), 256, 0, stream>>>(x, Bbig, flag);
    conv3mm_k<<<dim3(98,NB), 256, 0, stream>>>(Bbig, Wpk, t3);
    dwconv_k<<<NB*CC, 256, 0, stream>>>(t3, w4, t3, flag);   // in-place
    t5_k    <<<dim3(32,NB), 256, 0, stream>>>(x, t5, flag);
    t15_k   <<<dim3(HH,4,NB), 256, 0, stream>>>(t3, Wf, u);  // u aliases dead Bbig
    final_k <<<dim3(HWS/64, CC/64, NB), 256, 0, stream>>>(x, t5, w9, u, d_out, flag);
}